// Round 12
// baseline (196.686 us; speedup 1.0000x reference)
//
#include <hip/hip_runtime.h>
#include <stdint.h>

// MHA: B=8,S=1024,D=128,H=8,HD=1024. Inputs fp32, mask int32, OUTPUT fp32.
// R11 (resubmit; prior round hit GPUAcquisitionTimeout — never ran).
// Transposed-MFMA pipelines. Identity used everywhere: 16x16 C-layout
// (row=q*4+reg, col=l) == K=16 B-operand layout (k=q*4+j, n=l). Attention
// computes S^T = K·Q^T and O^T = V^T·P^T (mfma 16x16x16bf16_1k) so P stays
// in registers (no LDS round-trip). qkv/out_proj compute C^T for direct
// vectorized stores (no LDS transpose). Covered-drain DMA skeleton from R10.
// ws (~65MB): Qg/Kg (B,H,S,D) bf16, Vtg (B,H,D,S) bf16, AO (B,S,HD) bf16,
//             then WTq,WTk,WTv (1024x128), WoT (128x1024) bf16.

typedef __attribute__((ext_vector_type(8))) short bf16x8;
typedef __attribute__((ext_vector_type(4))) short s16x4;
typedef __attribute__((ext_vector_type(4))) float f32x4;
typedef unsigned int uint;
typedef unsigned short ushort;

#if __has_builtin(__builtin_amdgcn_mfma_f32_16x16x16bf16_1k)
#define HAVE_MFMA16 1
#define MFMA16(a, b, c) __builtin_amdgcn_mfma_f32_16x16x16bf16_1k(a, b, c, 0, 0, 0)
#endif

__device__ __forceinline__ float bf2f(short s) {
    return __uint_as_float(((uint)(ushort)s) << 16);
}
__device__ __forceinline__ short f2bf(float f) {   // RNE
    uint u = __float_as_uint(f);
    u += 0x7fffu + ((u >> 16) & 1u);
    return (short)(u >> 16);
}
__device__ __forceinline__ short f2bf_fast(float f) {  // round-half-up (p>=0)
    return (short)((__float_as_uint(f) + 0x8000u) >> 16);
}

// async global->LDS DMA, 16B/lane; LDS dest = wave-uniform base + lane*16
__device__ __forceinline__ void dma16(const short* g, short* l) {
    __builtin_amdgcn_global_load_lds(
        (const __attribute__((address_space(1))) uint*)g,
        (__attribute__((address_space(3))) uint*)l, 16, 0, 0);
}

// ---------------------------------------------------------------- probe ----
__global__ __launch_bounds__(256) void fill_sentinel(float* __restrict__ out, int n) {
    int i = blockIdx.x * 256 + threadIdx.x;
    if (i < n) out[i] = 128.0f;
}

// ---------------------------------------------------------------- prep ----
__global__ __launch_bounds__(256) void transpose_w(
    const float* __restrict__ Wq, const float* __restrict__ Wk,
    const float* __restrict__ Wv, const float* __restrict__ Wo,
    short* __restrict__ WTq, short* __restrict__ WTk,
    short* __restrict__ WTv, short* __restrict__ WoT)
{
    int z = blockIdx.y;
    const float* src; short* dst; int K, N;
    if (z < 3) { K = 128; N = 1024; src = (z==0)?Wq:(z==1)?Wk:Wv; dst = (z==0)?WTq:(z==1)?WTk:WTv; }
    else       { K = 1024; N = 128; src = Wo; dst = WoT; }
    int ntn = N >> 6;
    int nt = blockIdx.x % ntn, kt = blockIdx.x / ntn;
    int k0 = kt * 64, n0 = nt * 64;

    __shared__ __align__(16) short TT[64][72];
    int t = threadIdx.x;
    int r = t >> 2, c4 = t & 3;
    const float4* s4 = (const float4*)&src[(k0 + r) * N + n0 + c4 * 16];
    short* tr = &TT[r][c4 * 16];
#pragma unroll
    for (int i = 0; i < 4; ++i) {
        float4 v = s4[i];
        tr[i * 4 + 0] = f2bf(v.x);
        tr[i * 4 + 1] = f2bf(v.y);
        tr[i * 4 + 2] = f2bf(v.z);
        tr[i * 4 + 3] = f2bf(v.w);
    }
    __syncthreads();
    union { short s[16]; uint4 v[2]; } pk;
#pragma unroll
    for (int i = 0; i < 16; ++i) pk.s[i] = TT[c4 * 16 + i][r];
    uint4* dp = (uint4*)&dst[(n0 + r) * K + k0 + c4 * 16];
    dp[0] = pk.v[0]; dp[1] = pk.v[1];
}

// ------------------------------------------------------------ qkv proj ----
// C^T = W^T-as-A x X-as-B per tile -> direct vectorized stores, no T array.
// nt-split: grid (256,3), 8 nt per block, LDS 49KB -> 3 blocks/CU.
__global__ __launch_bounds__(256) void qkv_proj(
    const float* __restrict__ query, const float* __restrict__ key_,
    const float* __restrict__ value, const float* __restrict__ pos,
    const short* __restrict__ WTq, const short* __restrict__ WTk, const short* __restrict__ WTv,
    const float* __restrict__ bq, const float* __restrict__ bk, const float* __restrict__ bv,
    short* __restrict__ Qg, short* __restrict__ Kg, short* __restrict__ Vtg)
{
    int z = blockIdx.y;
    const float* X    = (z==0) ? query : (z==1) ? key_ : value;
    const short* WT   = (z==0) ? WTq   : (z==1) ? WTk  : WTv;
    const float* bias = (z==0) ? bq    : (z==1) ? bk   : bv;

    __shared__ __align__(16) short Xs[64][136];
    __shared__ __align__(16) short Ws[2][8192];

    int t = threadIdx.x;
    int bx = blockIdx.x;
    int m0 = (bx >> 1) * 64;
    int nt0 = (bx & 1) * 8;
    int lane = t & 63, w = t >> 6;
    int l = lane & 15, q = lane >> 4;

    const short* wbase = &WT[(w * 16 + l) * 128 + q * 8];
    { // prefetch W(nt0)
#pragma unroll
        for (int k32 = 0; k32 < 4; ++k32)
            dma16(wbase + nt0 * 8192 + k32 * 32, &Ws[0][(w * 4 + k32) * 512]);
    }
    { // stage X = bf16(x+pos)
        int r = t >> 2, c4 = t & 3;
        const float4* xs = (const float4*)&X[(m0 + r) * 128 + c4 * 32];
        const float4* ps = (const float4*)&pos[(m0 + r) * 128 + c4 * 32];
#pragma unroll
        for (int i = 0; i < 8; ++i) {
            float4 a = xs[i], bb = ps[i];
            uint2 o;
            o.x = (uint)(ushort)f2bf(a.x + bb.x) | ((uint)(ushort)f2bf(a.y + bb.y) << 16);
            o.y = (uint)(ushort)f2bf(a.z + bb.z) | ((uint)(ushort)f2bf(a.w + bb.w) << 16);
            *(uint2*)&Xs[r][c4 * 32 + i * 4] = o;
        }
    }
    __syncthreads();   // Xs ready; W(nt0) drained

    bf16x8 aX[4];
#pragma unroll
    for (int k32 = 0; k32 < 4; ++k32)
        aX[k32] = *(const bf16x8*)&Xs[w * 16 + l][k32 * 32 + q * 8];

    int b = m0 >> 10, s0 = m0 & 1023;
    int srow = s0 + w * 16 + l;

    for (int i = 0; i < 8; ++i) {
        int nt = nt0 + i;
        int cur = i & 1;
        if (i) __syncthreads();   // drains W(nt) (issued prev iter, covered) + WAR
        if (i < 7) {
            const short* wsrc = wbase + (nt + 1) * 8192;
#pragma unroll
            for (int k32 = 0; k32 < 4; ++k32)
                dma16(wsrc + k32 * 32, &Ws[cur ^ 1][(w * 4 + k32) * 512]);
        }

        int n0 = nt * 64;
#pragma unroll
        for (int nb = 0; nb < 4; ++nb) {
            f32x4 c = {0.f, 0.f, 0.f, 0.f};
            const short* wf = &Ws[cur][nb * 2048 + lane * 8];
#pragma unroll
            for (int k32 = 0; k32 < 4; ++k32)
                c = __builtin_amdgcn_mfma_f32_16x16x32_bf16(*(const bf16x8*)(wf + k32 * 512), aX[k32], c, 0, 0, 0);
            // C^T: lane (l,q) holds rows n = n0+nb*16+q*4+r, col m-row = w*16+l
            const float* bip = &bias[n0 + nb * 16 + q * 4];
            if (z < 2) {
                short* dst = (z == 0) ? Qg : Kg;
                int n00 = n0 + nb * 16;
                int hh = n00 >> 7, d0 = (n00 & 127) + q * 4;
                s16x4 ov = { f2bf(c[0] + bip[0]), f2bf(c[1] + bip[1]),
                             f2bf(c[2] + bip[2]), f2bf(c[3] + bip[3]) };
                *(s16x4*)&dst[(((b * 8 + hh) * 1024 + srow) << 7) + d0] = ov;
            } else {
#pragma unroll
                for (int r = 0; r < 4; ++r) {
                    int n = n0 + nb * 16 + q * 4 + r;
                    int hh = n >> 7, dd = n & 127;
                    Vtg[(((b * 8 + hh) * 128 + dd) << 10) + srow] = f2bf(c[r] + bip[r]);
                }
            }
        }
    }
}

// ----------------------------------------------------------- attention ----
#if HAVE_MFMA16
// S^T = K·Q^T (swap operands), P^T stays in registers and feeds PV^T
// (O^T = V^T·P^T) via 16x16x16 MFMA: C-layout == K=16 B-layout. No P LDS.
// 128 q-rows/block, covered-drain K dbuf + V single (R10 skeleton).
__global__ __launch_bounds__(256, 2) void attention(
    const short* __restrict__ Qg, const short* __restrict__ Kg,
    const short* __restrict__ Vtg, const int* __restrict__ mask,
    short* __restrict__ AO)
{
    int bh = blockIdx.x & 63;
    int qt = blockIdx.x >> 6;
    int b = bh >> 3, h = bh & 7;
    int q0 = qt << 7;

    __shared__ __align__(16) short Ks[2][8192];   // blk(nb,k32)=nb*4+k32, +lane*8
    __shared__ __align__(16) short Vs[8192];      // blk(dt,k32)=dt*2+k32, +lane*8

    int t = threadIdx.x, lane = t & 63, w = t >> 6;
    int l = lane & 15, q = lane >> 4;
    int q2 = q >> 1, qodd = q & 1;

    const short* kbase = &Kg[((bh * 1024 + w * 16 + l) << 7) + q * 8];
    const short* vb0 = &Vtg[((bh * 128 + (2 * w) * 16 + l) << 10) + q * 8];
    const short* vb1 = &Vtg[((bh * 128 + (2 * w + 1) * 16 + l) << 10) + q * 8];
    const int* mrow = &mask[b * 1024];

    { // prologue: K(0)
        dma16(kbase,      &Ks[0][(w * 4 + 0) * 512]);
        dma16(kbase + 32, &Ks[0][(w * 4 + 1) * 512]);
        dma16(kbase + 64, &Ks[0][(w * 4 + 2) * 512]);
        dma16(kbase + 96, &Ks[0][(w * 4 + 3) * 512]);
    }

    bf16x8 aQ[2][4];
#pragma unroll
    for (int s = 0; s < 2; ++s) {
        const short* qp = &Qg[((bh * 1024 + q0 + w * 32 + s * 16 + l) << 7) + q * 8];
#pragma unroll
        for (int k32 = 0; k32 < 4; ++k32)
            aQ[s][k32] = *(const bf16x8*)(qp + k32 * 32);
    }

    f32x4 O[2][8];
#pragma unroll
    for (int s = 0; s < 2; ++s)
#pragma unroll
        for (int i = 0; i < 8; ++i) O[s][i] = {0.f, 0.f, 0.f, 0.f};
    f32x4 Ls[2] = {{0.f, 0.f, 0.f, 0.f}, {0.f, 0.f, 0.f, 0.f}};

    const short O1 = (short)0x3F80;
    const s16x4 ONES4 = {O1, O1, O1, O1};

    const float SL2E = 0.12752298917458827f;  // (1/sqrt(128)) * log2(e)
    const float MAXB = 44.0f;                 // fixed softmax max bound (log2)

    for (int kt = 0; kt < 16; ++kt) {
        int k0 = kt << 6;
        int cur = kt & 1;
        __syncthreads();   // A: prior PV reads of Vs done; K(kt) drained
        if (kt < 15) {
            const short* kp = kbase + (((kt + 1) << 6) << 7);
            dma16(kp,      &Ks[cur ^ 1][(w * 4 + 0) * 512]);
            dma16(kp + 32, &Ks[cur ^ 1][(w * 4 + 1) * 512]);
            dma16(kp + 64, &Ks[cur ^ 1][(w * 4 + 2) * 512]);
            dma16(kp + 96, &Ks[cur ^ 1][(w * 4 + 3) * 512]);
        }
        {
            dma16(vb0 + k0,      &Vs[(4 * w + 0) * 512]);
            dma16(vb0 + k0 + 32, &Vs[(4 * w + 1) * 512]);
            dma16(vb1 + k0,      &Vs[(4 * w + 2) * 512]);
            dma16(vb1 + k0 + 32, &Vs[(4 * w + 3) * 512]);
        }

        int mv = mrow[k0 + lane];
        bool allm = (__ballot(mv != 0) == ~0ull);

        // S^T = K·Q^T, exp2 in fixed-max log2 domain; P^T packed to regs
        s16x4 Pt[2][4];
#pragma unroll
        for (int nb = 0; nb < 4; ++nb) {
            bf16x8 kf[4];
            const short* kfp = &Ks[cur][nb * 2048 + lane * 8];
#pragma unroll
            for (int k32 = 0; k32 < 4; ++k32)
                kf[k32] = *(const bf16x8*)(kfp + k32 * 512);
#pragma unroll
            for (int s = 0; s < 2; ++s) {
                f32x4 c = {0.f, 0.f, 0.f, 0.f};
#pragma unroll
                for (int k32 = 0; k32 < 4; ++k32)
                    c = __builtin_amdgcn_mfma_f32_16x16x32_bf16(kf[k32], aQ[s][k32], c, 0, 0, 0);
                float p[4];
#pragma unroll
                for (int r = 0; r < 4; ++r)
                    p[r] = exp2f(fmaf(c[r], SL2E, -MAXB));
                if (!allm) {
#pragma unroll
                    for (int r = 0; r < 4; ++r)
                        if (!mrow[k0 + nb * 16 + q * 4 + r]) p[r] = 0.f;
                }
                Pt[s][nb] = { f2bf_fast(p[0]), f2bf_fast(p[1]),
                              f2bf_fast(p[2]), f2bf_fast(p[3]) };
            }
        }
        // row sums (cols of P^T): ones-as-A K=16 MFMAs; also adds drain cover
#pragma unroll
        for (int s = 0; s < 2; ++s)
#pragma unroll
            for (int nb = 0; nb < 4; ++nb)
                Ls[s] = MFMA16(ONES4, Pt[s][nb], Ls[s]);
        __syncthreads();   // B: drains V(kt)+K(kt+1); covered by QK/exp phase

        // PV^T: O^T = V^T·P^T, A=V-frag (b64 from Vs), B=Pt (registers!)
#pragma unroll
        for (int dt = 0; dt < 8; ++dt) {
            s16x4 vf[4];
#pragma unroll
            for (int ktile = 0; ktile < 4; ++ktile) {
                int blk = dt * 2 + (ktile >> 1);
                int lanep = l + 16 * (((ktile & 1) << 1) + q2);
                vf[ktile] = *(const s16x4*)&Vs[blk * 512 + lanep * 8 + qodd * 4];
            }
#pragma unroll
            for (int ktile = 0; ktile < 4; ++ktile)
#pragma unroll
                for (int s = 0; s < 2; ++s)
                    O[s][dt] = MFMA16(vf[ktile], Pt[s][ktile], O[s][dt]);
        }
    }

    // epilogue: lane (l,q) holds O^T[d=dt*16+q*4+r][qr=l]; Ls[s][*]=sum(qr=l)
#pragma unroll
    for (int s = 0; s < 2; ++s) {
        float rl = 1.0f / Ls[s][0];
        int srow = q0 + w * 32 + s * 16 + l;
#pragma unroll
        for (int dt = 0; dt < 8; ++dt) {
            s16x4 ov = { f2bf(O[s][dt][0] * rl), f2bf(O[s][dt][1] * rl),
                         f2bf(O[s][dt][2] * rl), f2bf(O[s][dt][3] * rl) };
            *(s16x4*)&AO[((b * 1024 + srow) << 10) + h * 128 + dt * 16 + q * 4] = ov;
        }
    }
}
#else
// Fallback: R10 attention (P via per-wave LDS), used only if the K=16
// bf16 MFMA builtin is unavailable.
__global__ __launch_bounds__(256, 2) void attention(
    const short* __restrict__ Qg, const short* __restrict__ Kg,
    const short* __restrict__ Vtg, const int* __restrict__ mask,
    short* __restrict__ AO)
{
    int bh = blockIdx.x & 63;
    int qt = blockIdx.x >> 6;
    int b = bh >> 3, h = bh & 7;
    int q0 = qt << 7;

    __shared__ __align__(16) short Ks[2][8192];
    __shared__ __align__(16) short Vs[8192];
    __shared__ __align__(16) short Ps[4][32][72];

    int t = threadIdx.x, lane = t & 63, w = t >> 6;
    int l = lane & 15, q = lane >> 4;

    const short* kbase = &Kg[((bh * 1024 + w * 16 + l) << 7) + q * 8];
    const short* vb0 = &Vtg[((bh * 128 + (2 * w) * 16 + l) << 10) + q * 8];
    const short* vb1 = &Vtg[((bh * 128 + (2 * w + 1) * 16 + l) << 10) + q * 8];
    const int* mrow = &mask[b * 1024];

    {
        dma16(kbase,      &Ks[0][(w * 4 + 0) * 512]);
        dma16(kbase + 32, &Ks[0][(w * 4 + 1) * 512]);
        dma16(kbase + 64, &Ks[0][(w * 4 + 2) * 512]);
        dma16(kbase + 96, &Ks[0][(w * 4 + 3) * 512]);
    }

    bf16x8 aQ[2][4];
#pragma unroll
    for (int s = 0; s < 2; ++s) {
        const short* qp = &Qg[((bh * 1024 + q0 + w * 32 + s * 16 + l) << 7) + q * 8];
#pragma unroll
        for (int k32 = 0; k32 < 4; ++k32)
            aQ[s][k32] = *(const bf16x8*)(qp + k32 * 32);
    }

    f32x4 O[2][8];
#pragma unroll
    for (int s = 0; s < 2; ++s)
#pragma unroll
        for (int i = 0; i < 8; ++i) O[s][i] = {0.f, 0.f, 0.f, 0.f};
    f32x4 Ls[2] = {{0.f, 0.f, 0.f, 0.f}, {0.f, 0.f, 0.f, 0.f}};

    const short O1 = (short)0x3F80;
    const bf16x8 ONES = {O1, O1, O1, O1, O1, O1, O1, O1};

    const float SL2E = 0.12752298917458827f;
    const float MAXB = 44.0f;

    for (int kt = 0; kt < 16; ++kt) {
        int k0 = kt << 6;
        int cur = kt & 1;
        __syncthreads();
        if (kt < 15) {
            const short* kp = kbase + (((kt + 1) << 6) << 7);
            dma16(kp,      &Ks[cur ^ 1][(w * 4 + 0) * 512]);
            dma16(kp + 32, &Ks[cur ^ 1][(w * 4 + 1) * 512]);
            dma16(kp + 64, &Ks[cur ^ 1][(w * 4 + 2) * 512]);
            dma16(kp + 96, &Ks[cur ^ 1][(w * 4 + 3) * 512]);
        }
        {
            dma16(vb0 + k0,      &Vs[(4 * w + 0) * 512]);
            dma16(vb0 + k0 + 32, &Vs[(4 * w + 1) * 512]);
            dma16(vb1 + k0,      &Vs[(4 * w + 2) * 512]);
            dma16(vb1 + k0 + 32, &Vs[(4 * w + 3) * 512]);
        }

        int mk[4];
#pragma unroll
        for (int nb = 0; nb < 4; ++nb) mk[nb] = mrow[k0 + nb * 16 + l];
        bool allm = (__ballot(mk[0] && mk[1] && mk[2] && mk[3]) == ~0ull);

#pragma unroll
        for (int nb = 0; nb < 4; ++nb) {
            bf16x8 kf[4];
            const short* kfp = &Ks[cur][nb * 2048 + lane * 8];
#pragma unroll
            for (int k32 = 0; k32 < 4; ++k32)
                kf[k32] = *(const bf16x8*)(kfp + k32 * 512);
#pragma unroll
            for (int s = 0; s < 2; ++s) {
                f32x4 c = {0.f, 0.f, 0.f, 0.f};
#pragma unroll
                for (int k32 = 0; k32 < 4; ++k32)
                    c = __builtin_amdgcn_mfma_f32_16x16x32_bf16(aQ[s][k32], kf[k32], c, 0, 0, 0);
#pragma unroll
                for (int r = 0; r < 4; ++r) {
                    float pv = exp2f(fmaf(c[r], SL2E, -MAXB));
                    if (!allm) pv = mk[nb] ? pv : 0.f;
                    Ps[w][s * 16 + q * 4 + r][nb * 16 + l] = f2bf_fast(pv);
                }
            }
        }
        __syncthreads();

        bf16x8 aP[2][2];
#pragma unroll
        for (int s = 0; s < 2; ++s) {
            aP[s][0] = *(const bf16x8*)&Ps[w][s * 16 + l][q * 8];
            aP[s][1] = *(const bf16x8*)&Ps[w][s * 16 + l][32 + q * 8];
        }
#pragma unroll
        for (int s = 0; s < 2; ++s) {
            Ls[s] = __builtin_amdgcn_mfma_f32_16x16x32_bf16(aP[s][0], ONES, Ls[s], 0, 0, 0);
            Ls[s] = __builtin_amdgcn_mfma_f32_16x16x32_bf16(aP[s][1], ONES, Ls[s], 0, 0, 0);
        }
#pragma unroll
        for (int dt = 0; dt < 8; ++dt) {
            bf16x8 vf0 = *(const bf16x8*)&Vs[(dt * 2 + 0) * 512 + lane * 8];
            bf16x8 vf1 = *(const bf16x8*)&Vs[(dt * 2 + 1) * 512 + lane * 8];
#pragma unroll
            for (int s = 0; s < 2; ++s) {
                f32x4 c = O[s][dt];
                c = __builtin_amdgcn_mfma_f32_16x16x32_bf16(aP[s][0], vf0, c, 0, 0, 0);
                c = __builtin_amdgcn_mfma_f32_16x16x32_bf16(aP[s][1], vf1, c, 0, 0, 0);
                O[s][dt] = c;
            }
        }
    }

#pragma unroll
    for (int s = 0; s < 2; ++s) {
        float rl[4];
#pragma unroll
        for (int r = 0; r < 4; ++r) rl[r] = 1.0f / Ls[s][r];
#pragma unroll
        for (int dt = 0; dt < 8; ++dt) {
            int col = h * 128 + dt * 16 + l;
#pragma unroll
            for (int r = 0; r < 4; ++r) {
                int srow = q0 + w * 32 + s * 16 + q * 4 + r;
                AO[((b * 1024 + srow) << 10) + col] = f2bf(O[s][dt][r] * rl[r]);
            }
        }
    }
}
#endif

// ------------------------------------------------------------ out proj ----
// C^T orientation (A=WoT-frag, B=AO-frag) -> float4 stores. 16-row m-tiles,
// grid 512. Double-buffered As (VGPR-parked) + Bs (DMA): 1 barrier/kc.
__global__ __launch_bounds__(256) void out_proj(
    const short* __restrict__ AO, const short* __restrict__ WoT,
    const float* __restrict__ bo, float* __restrict__ out)
{
    __shared__ __align__(16) short As[2][16][72];
    __shared__ __align__(16) short Bs[2][8192];   // blk(nb,k32)=nb*2+k32, nb 0..7

    int t = threadIdx.x, lane = t & 63, w = t >> 6;
    int l = lane & 15, q = lane >> 4;
    int m0 = blockIdx.x * 16;

    int ar = t >> 3, ac8 = t & 7;
    {
        if (t < 128)
            *(uint4*)&As[0][ar][ac8 * 8] = *(const uint4*)&AO[((m0 + ar) << 10) + ac8 * 8];
#pragma unroll
        for (int j = 0; j < 4; ++j) {
            int nb = 2 * w + (j >> 1), k32 = j & 1;
            dma16(&WoT[(nb * 16 + l) * 1024 + k32 * 32 + q * 8], &Bs[0][(nb * 2 + k32) * 512]);
        }
    }

    f32x4 acc[2];
    acc[0] = {0.f, 0.f, 0.f, 0.f};
    acc[1] = {0.f, 0.f, 0.f, 0.f};

    for (int kc = 0; kc < 16; ++kc) {
        __syncthreads();
        int cur = kc & 1;
        uint4 anext;
        if (kc < 15) {
            int k1 = (kc + 1) * 64;
            if (t < 128)
                anext = *(const uint4*)&AO[((m0 + ar) << 10) + k1 + ac8 * 8];
#pragma unroll
            for (int j = 0; j < 4; ++j) {
                int nb = 2 * w + (j >> 1), k32 = j & 1;
                dma16(&WoT[(nb * 16 + l) * 1024 + k1 + k32 * 32 + q * 8],
                      &Bs[cur ^ 1][(nb * 2 + k32) * 512]);
            }
        }

        bf16x8 aA0 = *(const bf16x8*)&As[cur][l][q * 8];
        bf16x8 aA1 = *(const bf16x8*)&As[cur][l][32 + q * 8];
#pragma unroll
        for (int nb = 0; nb < 2; ++nb) {
            int nbg = 2 * w + nb;
            f32x4 c = acc[nb];
            c = __builtin_amdgcn_mfma_f32_16x16x32_bf16(*(const bf16x8*)&Bs[cur][(nbg * 2 + 0) * 512 + lane * 8], aA0, c, 0, 0, 0);
            c = __builtin_amdgcn_mfma_f32_16x16x32_bf16(*(const bf16x8*)&Bs[cur][(nbg * 2 + 1) * 512 + lane * 8], aA1, c, 0, 0, 0);
            acc[nb] = c;
        }

        if (kc < 15 && t < 128)
            *(uint4*)&As[cur ^ 1][ar][ac8 * 8] = anext;
    }

    // C^T: lane (l,q) holds out[n=(2w+nb)*16+q*4+r][m=m0+l] -> float4 stores
#pragma unroll
    for (int nb = 0; nb < 2; ++nb) {
        int n0 = (2 * w + nb) * 16 + q * 4;
        const float* bop = &bo[n0];
        float4 ov = { acc[nb][0] + bop[0], acc[nb][1] + bop[1],
                      acc[nb][2] + bop[2], acc[nb][3] + bop[3] };
        *(float4*)&out[((m0 + l) << 7) + n0] = ov;
    }
}

// -------------------------------------------------------------- launch ----
extern "C" void kernel_launch(void* const* d_in, const int* in_sizes, int n_in,
                              void* d_out, int out_size, void* d_ws, size_t ws_size,
                              hipStream_t stream)
{
    const size_t NEED = (size_t)65 * 1024 * 1024;
    if (ws_size < NEED) {
        hipLaunchKernelGGL(fill_sentinel, dim3((out_size + 255) / 256), dim3(256), 0, stream,
                           (float*)d_out, out_size);
        return;
    }

    const float* query = (const float*)d_in[0];
    const float* key_  = (const float*)d_in[1];
    const float* value = (const float*)d_in[2];
    const float* pos   = (const float*)d_in[3];
    const int*   mask  = (const int*)d_in[4];
    const float* Wq = (const float*)d_in[5];
    const float* bq = (const float*)d_in[6];
    const float* Wk = (const float*)d_in[7];
    const float* bk = (const float*)d_in[8];
    const float* Wv = (const float*)d_in[9];
    const float* bv = (const float*)d_in[10];
    const float* Wo = (const float*)d_in[11];
    const float* bo = (const float*)d_in[12];

    char* ws = (char*)d_ws;
    short* Qg  = (short*)(ws);
    short* Kg  = (short*)(ws + (size_t)16 * 1024 * 1024);
    short* Vtg = (short*)(ws + (size_t)32 * 1024 * 1024);
    short* AO  = (short*)(ws + (size_t)48 * 1024 * 1024);
    short* WTq = (short*)(ws + (size_t)64 * 1024 * 1024);
    short* WTk = WTq + 131072;
    short* WTv = WTk + 131072;
    short* WoT = WTv + 131072;

    hipLaunchKernelGGL(transpose_w, dim3(32, 4), dim3(256), 0, stream,
                       Wq, Wk, Wv, Wo, WTq, WTk, WTv, WoT);
    hipLaunchKernelGGL(qkv_proj, dim3(256, 3), dim3(256), 0, stream,
                       query, key_, value, pos, WTq, WTk, WTv, bq, bk, bv, Qg, Kg, Vtg);
    hipLaunchKernelGGL(attention, dim3(512), dim3(256), 0, stream,
                       Qg, Kg, Vtg, mask, AO);
    hipLaunchKernelGGL(out_proj, dim3(512), dim3(256), 0, stream,
                       AO, WoT, bo, (float*)d_out);
}

// Round 13
// 194.501 us; speedup vs baseline: 1.0112x; 1.0112x over previous
//
#include <hip/hip_runtime.h>
#include <stdint.h>

// MHA: B=8,S=1024,D=128,H=8,HD=1024. Inputs fp32, mask int32, OUTPUT fp32.
// R13 consolidation: R10's attention (best measured: 64.3us — K=32 PV via
// per-wave LDS P; K=16 register-P was rate-limited + 4-way-conflicted, R12)
// + R12's qkv/out_proj (C^T epilogues, measured -3.3us residual).
// Lesson encoded: with dma16's lane*16B runs, only full-run b128 LDS reads
// are conflict-free; 8B sub-run reads are structurally >=4-way conflicted.
// ws (~65MB): Qg/Kg (B,H,S,D) bf16, Vtg (B,H,D,S) bf16, AO (B,S,HD) bf16,
//             then WTq,WTk,WTv (1024x128), WoT (128x1024) bf16.

typedef __attribute__((ext_vector_type(8))) short bf16x8;
typedef __attribute__((ext_vector_type(4))) short s16x4;
typedef __attribute__((ext_vector_type(4))) float f32x4;
typedef unsigned int uint;
typedef unsigned short ushort;

__device__ __forceinline__ float bf2f(short s) {
    return __uint_as_float(((uint)(ushort)s) << 16);
}
__device__ __forceinline__ short f2bf(float f) {   // RNE
    uint u = __float_as_uint(f);
    u += 0x7fffu + ((u >> 16) & 1u);
    return (short)(u >> 16);
}
__device__ __forceinline__ short f2bf_fast(float f) {  // round-half-up (p>=0)
    return (short)((__float_as_uint(f) + 0x8000u) >> 16);
}

// async global->LDS DMA, 16B/lane; LDS dest = wave-uniform base + lane*16
__device__ __forceinline__ void dma16(const short* g, short* l) {
    __builtin_amdgcn_global_load_lds(
        (const __attribute__((address_space(1))) uint*)g,
        (__attribute__((address_space(3))) uint*)l, 16, 0, 0);
}

// ---------------------------------------------------------------- probe ----
__global__ __launch_bounds__(256) void fill_sentinel(float* __restrict__ out, int n) {
    int i = blockIdx.x * 256 + threadIdx.x;
    if (i < n) out[i] = 128.0f;
}

// ---------------------------------------------------------------- prep ----
__global__ __launch_bounds__(256) void transpose_w(
    const float* __restrict__ Wq, const float* __restrict__ Wk,
    const float* __restrict__ Wv, const float* __restrict__ Wo,
    short* __restrict__ WTq, short* __restrict__ WTk,
    short* __restrict__ WTv, short* __restrict__ WoT)
{
    int z = blockIdx.y;
    const float* src; short* dst; int K, N;
    if (z < 3) { K = 128; N = 1024; src = (z==0)?Wq:(z==1)?Wk:Wv; dst = (z==0)?WTq:(z==1)?WTk:WTv; }
    else       { K = 1024; N = 128; src = Wo; dst = WoT; }
    int ntn = N >> 6;
    int nt = blockIdx.x % ntn, kt = blockIdx.x / ntn;
    int k0 = kt * 64, n0 = nt * 64;

    __shared__ __align__(16) short TT[64][72];
    int t = threadIdx.x;
    int r = t >> 2, c4 = t & 3;
    const float4* s4 = (const float4*)&src[(k0 + r) * N + n0 + c4 * 16];
    short* tr = &TT[r][c4 * 16];
#pragma unroll
    for (int i = 0; i < 4; ++i) {
        float4 v = s4[i];
        tr[i * 4 + 0] = f2bf(v.x);
        tr[i * 4 + 1] = f2bf(v.y);
        tr[i * 4 + 2] = f2bf(v.z);
        tr[i * 4 + 3] = f2bf(v.w);
    }
    __syncthreads();
    union { short s[16]; uint4 v[2]; } pk;
#pragma unroll
    for (int i = 0; i < 16; ++i) pk.s[i] = TT[c4 * 16 + i][r];
    uint4* dp = (uint4*)&dst[(n0 + r) * K + k0 + c4 * 16];
    dp[0] = pk.v[0]; dp[1] = pk.v[1];
}

// ------------------------------------------------------------ qkv proj ----
// C^T = W^T-as-A x X-as-B per tile -> direct vectorized stores, no T array.
// nt-split: grid (256,3), 8 nt per block.
__global__ __launch_bounds__(256) void qkv_proj(
    const float* __restrict__ query, const float* __restrict__ key_,
    const float* __restrict__ value, const float* __restrict__ pos,
    const short* __restrict__ WTq, const short* __restrict__ WTk, const short* __restrict__ WTv,
    const float* __restrict__ bq, const float* __restrict__ bk, const float* __restrict__ bv,
    short* __restrict__ Qg, short* __restrict__ Kg, short* __restrict__ Vtg)
{
    int z = blockIdx.y;
    const float* X    = (z==0) ? query : (z==1) ? key_ : value;
    const short* WT   = (z==0) ? WTq   : (z==1) ? WTk  : WTv;
    const float* bias = (z==0) ? bq    : (z==1) ? bk   : bv;

    __shared__ __align__(16) short Xs[64][136];
    __shared__ __align__(16) short Ws[2][8192];

    int t = threadIdx.x;
    int bx = blockIdx.x;
    int m0 = (bx >> 1) * 64;
    int nt0 = (bx & 1) * 8;
    int lane = t & 63, w = t >> 6;
    int l = lane & 15, q = lane >> 4;

    const short* wbase = &WT[(w * 16 + l) * 128 + q * 8];
    { // prefetch W(nt0)
#pragma unroll
        for (int k32 = 0; k32 < 4; ++k32)
            dma16(wbase + nt0 * 8192 + k32 * 32, &Ws[0][(w * 4 + k32) * 512]);
    }
    { // stage X = bf16(x+pos)
        int r = t >> 2, c4 = t & 3;
        const float4* xs = (const float4*)&X[(m0 + r) * 128 + c4 * 32];
        const float4* ps = (const float4*)&pos[(m0 + r) * 128 + c4 * 32];
#pragma unroll
        for (int i = 0; i < 8; ++i) {
            float4 a = xs[i], bb = ps[i];
            uint2 o;
            o.x = (uint)(ushort)f2bf(a.x + bb.x) | ((uint)(ushort)f2bf(a.y + bb.y) << 16);
            o.y = (uint)(ushort)f2bf(a.z + bb.z) | ((uint)(ushort)f2bf(a.w + bb.w) << 16);
            *(uint2*)&Xs[r][c4 * 32 + i * 4] = o;
        }
    }
    __syncthreads();   // Xs ready; W(nt0) drained

    bf16x8 aX[4];
#pragma unroll
    for (int k32 = 0; k32 < 4; ++k32)
        aX[k32] = *(const bf16x8*)&Xs[w * 16 + l][k32 * 32 + q * 8];

    int b = m0 >> 10, s0 = m0 & 1023;
    int srow = s0 + w * 16 + l;

    for (int i = 0; i < 8; ++i) {
        int nt = nt0 + i;
        int cur = i & 1;
        if (i) __syncthreads();   // drains W(nt) (issued prev iter, covered) + WAR
        if (i < 7) {
            const short* wsrc = wbase + (nt + 1) * 8192;
#pragma unroll
            for (int k32 = 0; k32 < 4; ++k32)
                dma16(wsrc + k32 * 32, &Ws[cur ^ 1][(w * 4 + k32) * 512]);
        }

        int n0 = nt * 64;
#pragma unroll
        for (int nb = 0; nb < 4; ++nb) {
            f32x4 c = {0.f, 0.f, 0.f, 0.f};
            const short* wf = &Ws[cur][nb * 2048 + lane * 8];
#pragma unroll
            for (int k32 = 0; k32 < 4; ++k32)
                c = __builtin_amdgcn_mfma_f32_16x16x32_bf16(*(const bf16x8*)(wf + k32 * 512), aX[k32], c, 0, 0, 0);
            // C^T: lane (l,q) holds rows n = n0+nb*16+q*4+r, col m-row = w*16+l
            const float* bip = &bias[n0 + nb * 16 + q * 4];
            if (z < 2) {
                short* dst = (z == 0) ? Qg : Kg;
                int n00 = n0 + nb * 16;
                int hh = n00 >> 7, d0 = (n00 & 127) + q * 4;
                s16x4 ov = { f2bf(c[0] + bip[0]), f2bf(c[1] + bip[1]),
                             f2bf(c[2] + bip[2]), f2bf(c[3] + bip[3]) };
                *(s16x4*)&dst[(((b * 8 + hh) * 1024 + srow) << 7) + d0] = ov;
            } else {
#pragma unroll
                for (int r = 0; r < 4; ++r) {
                    int n = n0 + nb * 16 + q * 4 + r;
                    int hh = n >> 7, dd = n & 127;
                    Vtg[(((b * 8 + hh) * 128 + dd) << 10) + srow] = f2bf(c[r] + bip[r]);
                }
            }
        }
    }
}

// ----------------------------------------------------------- attention ----
// R10 form (best measured). Flash attention, fixed-max softmax. 128 q-rows/
// block, 4 waves x 32 rows. K dbuf (prefetch kt+1 before QK), V single
// buffer; barrier B sits a full QK/exp phase after DMA issue -> covered
// drains. kf reg-cached per nb, vf (b128, conflict-free) shared across
// strips; P via per-wave LDS; row-sums via MFMA(P, ones).
__global__ __launch_bounds__(256, 2) void attention(
    const short* __restrict__ Qg, const short* __restrict__ Kg,
    const short* __restrict__ Vtg, const int* __restrict__ mask,
    short* __restrict__ AO)
{
    int bh = blockIdx.x & 63;          // q-tiles of one (b,h) share an XCD
    int qt = blockIdx.x >> 6;          // 0..7
    int b = bh >> 3, h = bh & 7;
    int q0 = qt << 7;                  // 128 q-rows per block

    __shared__ __align__(16) short Ks[2][8192];    // blk(nb,k32)=nb*4+k32, +lane*8
    __shared__ __align__(16) short Vs[8192];       // blk(dt,k32)=dt*2+k32, +lane*8
    __shared__ __align__(16) short Ps[4][32][72];  // per-wave P (2 strips)

    int t = threadIdx.x, lane = t & 63, w = t >> 6;
    int l = lane & 15, q = lane >> 4;

    const short* kbase = &Kg[((bh * 1024 + w * 16 + l) << 7) + q * 8];
    const short* vb0 = &Vtg[((bh * 128 + (2 * w) * 16 + l) << 10) + q * 8];
    const short* vb1 = &Vtg[((bh * 128 + (2 * w + 1) * 16 + l) << 10) + q * 8];
    const int* mrow = &mask[b * 1024];

    { // prologue: K(0) -> Ks[0]
        dma16(kbase,      &Ks[0][(w * 4 + 0) * 512]);
        dma16(kbase + 32, &Ks[0][(w * 4 + 1) * 512]);
        dma16(kbase + 64, &Ks[0][(w * 4 + 2) * 512]);
        dma16(kbase + 96, &Ks[0][(w * 4 + 3) * 512]);
    }

    bf16x8 aQ[2][4];
#pragma unroll
    for (int s = 0; s < 2; ++s) {
        const short* qp = &Qg[((bh * 1024 + q0 + w * 32 + s * 16 + l) << 7) + q * 8];
#pragma unroll
        for (int k32 = 0; k32 < 4; ++k32)
            aQ[s][k32] = *(const bf16x8*)(qp + k32 * 32);
    }

    f32x4 O[2][8];
#pragma unroll
    for (int s = 0; s < 2; ++s)
#pragma unroll
        for (int i = 0; i < 8; ++i) O[s][i] = {0.f, 0.f, 0.f, 0.f};
    f32x4 Ls[2] = {{0.f, 0.f, 0.f, 0.f}, {0.f, 0.f, 0.f, 0.f}};

    const short O1 = (short)0x3F80;    // bf16 1.0
    const bf16x8 ONES = {O1, O1, O1, O1, O1, O1, O1, O1};

    const float SL2E = 0.12752298917458827f;  // (1/sqrt(128)) * log2(e)
    const float MAXB = 44.0f;                 // fixed softmax max bound (log2)

    for (int kt = 0; kt < 16; ++kt) {
        int k0 = kt << 6;
        int cur = kt & 1;
        __syncthreads();   // A: prior PV reads of Vs done; K(kt) already drained
        if (kt < 15) {     // prefetch K(kt+1) -> alt buffer
            const short* kp = kbase + (((kt + 1) << 6) << 7);
            dma16(kp,      &Ks[cur ^ 1][(w * 4 + 0) * 512]);
            dma16(kp + 32, &Ks[cur ^ 1][(w * 4 + 1) * 512]);
            dma16(kp + 64, &Ks[cur ^ 1][(w * 4 + 2) * 512]);
            dma16(kp + 96, &Ks[cur ^ 1][(w * 4 + 3) * 512]);
        }
        { // V(kt) -> Vs (drained at barrier B, after the QK/exp phase)
            dma16(vb0 + k0,      &Vs[(4 * w + 0) * 512]);
            dma16(vb0 + k0 + 32, &Vs[(4 * w + 1) * 512]);
            dma16(vb1 + k0,      &Vs[(4 * w + 2) * 512]);
            dma16(vb1 + k0 + 32, &Vs[(4 * w + 3) * 512]);
        }

        int mk[4];
#pragma unroll
        for (int nb = 0; nb < 4; ++nb) mk[nb] = mrow[k0 + nb * 16 + l];
        bool allm = (__ballot(mk[0] && mk[1] && mk[2] && mk[3]) == ~0ull);

        // QK^T + exp2 + P to LDS; kf loaded once per nb, reused for both strips
#pragma unroll
        for (int nb = 0; nb < 4; ++nb) {
            bf16x8 kf[4];
            const short* kfp = &Ks[cur][nb * 2048 + lane * 8];
#pragma unroll
            for (int k32 = 0; k32 < 4; ++k32)
                kf[k32] = *(const bf16x8*)(kfp + k32 * 512);
#pragma unroll
            for (int s = 0; s < 2; ++s) {
                f32x4 c = {0.f, 0.f, 0.f, 0.f};
#pragma unroll
                for (int k32 = 0; k32 < 4; ++k32)
                    c = __builtin_amdgcn_mfma_f32_16x16x32_bf16(aQ[s][k32], kf[k32], c, 0, 0, 0);
#pragma unroll
                for (int r = 0; r < 4; ++r) {
                    float pv = exp2f(fmaf(c[r], SL2E, -MAXB));
                    if (!allm) pv = mk[nb] ? pv : 0.f;
                    Ps[w][s * 16 + q * 4 + r][nb * 16 + l] = f2bf_fast(pv);
                }
            }
        }
        __syncthreads();   // B: drains V(kt) + K(kt+1); covered by QK/exp phase

        bf16x8 aP[2][2];
#pragma unroll
        for (int s = 0; s < 2; ++s) {
            aP[s][0] = *(const bf16x8*)&Ps[w][s * 16 + l][q * 8];
            aP[s][1] = *(const bf16x8*)&Ps[w][s * 16 + l][32 + q * 8];
        }
#pragma unroll
        for (int s = 0; s < 2; ++s) {  // row sums: P @ ones
            Ls[s] = __builtin_amdgcn_mfma_f32_16x16x32_bf16(aP[s][0], ONES, Ls[s], 0, 0, 0);
            Ls[s] = __builtin_amdgcn_mfma_f32_16x16x32_bf16(aP[s][1], ONES, Ls[s], 0, 0, 0);
        }
        // PV: vf loaded once per dt (full-run b128 = conflict-free)
#pragma unroll
        for (int dt = 0; dt < 8; ++dt) {
            bf16x8 vf0 = *(const bf16x8*)&Vs[(dt * 2 + 0) * 512 + lane * 8];
            bf16x8 vf1 = *(const bf16x8*)&Vs[(dt * 2 + 1) * 512 + lane * 8];
#pragma unroll
            for (int s = 0; s < 2; ++s) {
                f32x4 c = O[s][dt];
                c = __builtin_amdgcn_mfma_f32_16x16x32_bf16(aP[s][0], vf0, c, 0, 0, 0);
                c = __builtin_amdgcn_mfma_f32_16x16x32_bf16(aP[s][1], vf1, c, 0, 0, 0);
                O[s][dt] = c;
            }
        }
    }

#pragma unroll
    for (int s = 0; s < 2; ++s) {
        float rl[4];
#pragma unroll
        for (int r = 0; r < 4; ++r) rl[r] = 1.0f / Ls[s][r];
#pragma unroll
        for (int dt = 0; dt < 8; ++dt) {
            int col = h * 128 + dt * 16 + l;
#pragma unroll
            for (int r = 0; r < 4; ++r) {
                int srow = q0 + w * 32 + s * 16 + q * 4 + r;
                AO[((b * 1024 + srow) << 10) + col] = f2bf(O[s][dt][r] * rl[r]);
            }
        }
    }
}

// ------------------------------------------------------------ out proj ----
// C^T orientation (A=WoT-frag, B=AO-frag) -> float4 stores. 16-row m-tiles,
// grid 512. Double-buffered As (VGPR-parked) + Bs (DMA): 1 barrier/kc.
__global__ __launch_bounds__(256) void out_proj(
    const short* __restrict__ AO, const short* __restrict__ WoT,
    const float* __restrict__ bo, float* __restrict__ out)
{
    __shared__ __align__(16) short As[2][16][72];
    __shared__ __align__(16) short Bs[2][8192];   // blk(nb,k32)=nb*2+k32, nb 0..7

    int t = threadIdx.x, lane = t & 63, w = t >> 6;
    int l = lane & 15, q = lane >> 4;
    int m0 = blockIdx.x * 16;

    int ar = t >> 3, ac8 = t & 7;
    {
        if (t < 128)
            *(uint4*)&As[0][ar][ac8 * 8] = *(const uint4*)&AO[((m0 + ar) << 10) + ac8 * 8];
#pragma unroll
        for (int j = 0; j < 4; ++j) {
            int nb = 2 * w + (j >> 1), k32 = j & 1;
            dma16(&WoT[(nb * 16 + l) * 1024 + k32 * 32 + q * 8], &Bs[0][(nb * 2 + k32) * 512]);
        }
    }

    f32x4 acc[2];
    acc[0] = {0.f, 0.f, 0.f, 0.f};
    acc[1] = {0.f, 0.f, 0.f, 0.f};

    for (int kc = 0; kc < 16; ++kc) {
        __syncthreads();
        int cur = kc & 1;
        uint4 anext;
        if (kc < 15) {
            int k1 = (kc + 1) * 64;
            if (t < 128)
                anext = *(const uint4*)&AO[((m0 + ar) << 10) + k1 + ac8 * 8];
#pragma unroll
            for (int j = 0; j < 4; ++j) {
                int nb = 2 * w + (j >> 1), k32 = j & 1;
                dma16(&WoT[(nb * 16 + l) * 1024 + k1 + k32 * 32 + q * 8],
                      &Bs[cur ^ 1][(nb * 2 + k32) * 512]);
            }
        }

        bf16x8 aA0 = *(const bf16x8*)&As[cur][l][q * 8];
        bf16x8 aA1 = *(const bf16x8*)&As[cur][l][32 + q * 8];
#pragma unroll
        for (int nb = 0; nb < 2; ++nb) {
            int nbg = 2 * w + nb;
            f32x4 c = acc[nb];
            c = __builtin_amdgcn_mfma_f32_16x16x32_bf16(*(const bf16x8*)&Bs[cur][(nbg * 2 + 0) * 512 + lane * 8], aA0, c, 0, 0, 0);
            c = __builtin_amdgcn_mfma_f32_16x16x32_bf16(*(const bf16x8*)&Bs[cur][(nbg * 2 + 1) * 512 + lane * 8], aA1, c, 0, 0, 0);
            acc[nb] = c;
        }

        if (kc < 15 && t < 128)
            *(uint4*)&As[cur ^ 1][ar][ac8 * 8] = anext;
    }

    // C^T: lane (l,q) holds out[n=(2w+nb)*16+q*4+r][m=m0+l] -> float4 stores
#pragma unroll
    for (int nb = 0; nb < 2; ++nb) {
        int n0 = (2 * w + nb) * 16 + q * 4;
        const float* bop = &bo[n0];
        float4 ov = { acc[nb][0] + bop[0], acc[nb][1] + bop[1],
                      acc[nb][2] + bop[2], acc[nb][3] + bop[3] };
        *(float4*)&out[((m0 + l) << 7) + n0] = ov;
    }
}

// -------------------------------------------------------------- launch ----
extern "C" void kernel_launch(void* const* d_in, const int* in_sizes, int n_in,
                              void* d_out, int out_size, void* d_ws, size_t ws_size,
                              hipStream_t stream)
{
    const size_t NEED = (size_t)65 * 1024 * 1024;
    if (ws_size < NEED) {
        hipLaunchKernelGGL(fill_sentinel, dim3((out_size + 255) / 256), dim3(256), 0, stream,
                           (float*)d_out, out_size);
        return;
    }

    const float* query = (const float*)d_in[0];
    const float* key_  = (const float*)d_in[1];
    const float* value = (const float*)d_in[2];
    const float* pos   = (const float*)d_in[3];
    const int*   mask  = (const int*)d_in[4];
    const float* Wq = (const float*)d_in[5];
    const float* bq = (const float*)d_in[6];
    const float* Wk = (const float*)d_in[7];
    const float* bk = (const float*)d_in[8];
    const float* Wv = (const float*)d_in[9];
    const float* bv = (const float*)d_in[10];
    const float* Wo = (const float*)d_in[11];
    const float* bo = (const float*)d_in[12];

    char* ws = (char*)d_ws;
    short* Qg  = (short*)(ws);
    short* Kg  = (short*)(ws + (size_t)16 * 1024 * 1024);
    short* Vtg = (short*)(ws + (size_t)32 * 1024 * 1024);
    short* AO  = (short*)(ws + (size_t)48 * 1024 * 1024);
    short* WTq = (short*)(ws + (size_t)64 * 1024 * 1024);
    short* WTk = WTq + 131072;
    short* WTv = WTk + 131072;
    short* WoT = WTv + 131072;

    hipLaunchKernelGGL(transpose_w, dim3(32, 4), dim3(256), 0, stream,
                       Wq, Wk, Wv, Wo, WTq, WTk, WTv, WoT);
    hipLaunchKernelGGL(qkv_proj, dim3(256, 3), dim3(256), 0, stream,
                       query, key_, value, pos, WTq, WTk, WTv, bq, bk, bv, Qg, Kg, Vtg);
    hipLaunchKernelGGL(attention, dim3(512), dim3(256), 0, stream,
                       Qg, Kg, Vtg, mask, AO);
    hipLaunchKernelGGL(out_proj, dim3(512), dim3(256), 0, stream,
                       AO, WoT, bo, (float*)d_out);
}

// Round 14
// 189.728 us; speedup vs baseline: 1.0367x; 1.0252x over previous
//
#include <hip/hip_runtime.h>
#include <stdint.h>

// MHA: B=8,S=1024,D=128,H=8,HD=1024. Inputs fp32, mask int32, OUTPUT fp32.
// R14 = R13 + qkv z==2 fix: V^T epilogue goes through Xs-reused-as-T LDS
// transpose -> 2x uint4 coalesced stores (was 16 scalar 2B global stores).
// attention = R10 form (best measured; 64-78us host-dependent).
// ws (~65MB): Qg/Kg (B,H,S,D) bf16, Vtg (B,H,D,S) bf16, AO (B,S,HD) bf16,
//             then WTq,WTk,WTv (1024x128), WoT (128x1024) bf16.

typedef __attribute__((ext_vector_type(8))) short bf16x8;
typedef __attribute__((ext_vector_type(4))) short s16x4;
typedef __attribute__((ext_vector_type(4))) float f32x4;
typedef unsigned int uint;
typedef unsigned short ushort;

__device__ __forceinline__ float bf2f(short s) {
    return __uint_as_float(((uint)(ushort)s) << 16);
}
__device__ __forceinline__ short f2bf(float f) {   // RNE
    uint u = __float_as_uint(f);
    u += 0x7fffu + ((u >> 16) & 1u);
    return (short)(u >> 16);
}
__device__ __forceinline__ short f2bf_fast(float f) {  // round-half-up (p>=0)
    return (short)((__float_as_uint(f) + 0x8000u) >> 16);
}

// async global->LDS DMA, 16B/lane; LDS dest = wave-uniform base + lane*16
__device__ __forceinline__ void dma16(const short* g, short* l) {
    __builtin_amdgcn_global_load_lds(
        (const __attribute__((address_space(1))) uint*)g,
        (__attribute__((address_space(3))) uint*)l, 16, 0, 0);
}

// ---------------------------------------------------------------- probe ----
__global__ __launch_bounds__(256) void fill_sentinel(float* __restrict__ out, int n) {
    int i = blockIdx.x * 256 + threadIdx.x;
    if (i < n) out[i] = 128.0f;
}

// ---------------------------------------------------------------- prep ----
__global__ __launch_bounds__(256) void transpose_w(
    const float* __restrict__ Wq, const float* __restrict__ Wk,
    const float* __restrict__ Wv, const float* __restrict__ Wo,
    short* __restrict__ WTq, short* __restrict__ WTk,
    short* __restrict__ WTv, short* __restrict__ WoT)
{
    int z = blockIdx.y;
    const float* src; short* dst; int K, N;
    if (z < 3) { K = 128; N = 1024; src = (z==0)?Wq:(z==1)?Wk:Wv; dst = (z==0)?WTq:(z==1)?WTk:WTv; }
    else       { K = 1024; N = 128; src = Wo; dst = WoT; }
    int ntn = N >> 6;
    int nt = blockIdx.x % ntn, kt = blockIdx.x / ntn;
    int k0 = kt * 64, n0 = nt * 64;

    __shared__ __align__(16) short TT[64][72];
    int t = threadIdx.x;
    int r = t >> 2, c4 = t & 3;
    const float4* s4 = (const float4*)&src[(k0 + r) * N + n0 + c4 * 16];
    short* tr = &TT[r][c4 * 16];
#pragma unroll
    for (int i = 0; i < 4; ++i) {
        float4 v = s4[i];
        tr[i * 4 + 0] = f2bf(v.x);
        tr[i * 4 + 1] = f2bf(v.y);
        tr[i * 4 + 2] = f2bf(v.z);
        tr[i * 4 + 3] = f2bf(v.w);
    }
    __syncthreads();
    union { short s[16]; uint4 v[2]; } pk;
#pragma unroll
    for (int i = 0; i < 16; ++i) pk.s[i] = TT[c4 * 16 + i][r];
    uint4* dp = (uint4*)&dst[(n0 + r) * K + k0 + c4 * 16];
    dp[0] = pk.v[0]; dp[1] = pk.v[1];
}

// ------------------------------------------------------------ qkv proj ----
// C^T = W^T-as-A x X-as-B per tile. z<2: direct s16x4 stores (d-contiguous).
// z==2: V^T wants s-contiguous -> route C^T frags through Xs-reused-as-T
// (Xs is dead after aX register loads) -> 2x uint4 coalesced stores.
// nt-split: grid (256,3), 8 nt per block.
__global__ __launch_bounds__(256) void qkv_proj(
    const float* __restrict__ query, const float* __restrict__ key_,
    const float* __restrict__ value, const float* __restrict__ pos,
    const short* __restrict__ WTq, const short* __restrict__ WTk, const short* __restrict__ WTv,
    const float* __restrict__ bq, const float* __restrict__ bk, const float* __restrict__ bv,
    short* __restrict__ Qg, short* __restrict__ Kg, short* __restrict__ Vtg)
{
    int z = blockIdx.y;
    const float* X    = (z==0) ? query : (z==1) ? key_ : value;
    const short* WT   = (z==0) ? WTq   : (z==1) ? WTk  : WTv;
    const float* bias = (z==0) ? bq    : (z==1) ? bk   : bv;

    __shared__ __align__(16) short Xs[64][136];   // reused as T[64][72] for z==2
    __shared__ __align__(16) short Ws[2][8192];

    int t = threadIdx.x;
    int bx = blockIdx.x;
    int m0 = (bx >> 1) * 64;
    int nt0 = (bx & 1) * 8;
    int lane = t & 63, w = t >> 6;
    int l = lane & 15, q = lane >> 4;

    short* Tbuf = &Xs[0][0];          // T[n][m]: n*72 + m (9.2KB <= Xs)

    const short* wbase = &WT[(w * 16 + l) * 128 + q * 8];
    { // prefetch W(nt0)
#pragma unroll
        for (int k32 = 0; k32 < 4; ++k32)
            dma16(wbase + nt0 * 8192 + k32 * 32, &Ws[0][(w * 4 + k32) * 512]);
    }
    { // stage X = bf16(x+pos)
        int r = t >> 2, c4 = t & 3;
        const float4* xs = (const float4*)&X[(m0 + r) * 128 + c4 * 32];
        const float4* ps = (const float4*)&pos[(m0 + r) * 128 + c4 * 32];
#pragma unroll
        for (int i = 0; i < 8; ++i) {
            float4 a = xs[i], bb = ps[i];
            uint2 o;
            o.x = (uint)(ushort)f2bf(a.x + bb.x) | ((uint)(ushort)f2bf(a.y + bb.y) << 16);
            o.y = (uint)(ushort)f2bf(a.z + bb.z) | ((uint)(ushort)f2bf(a.w + bb.w) << 16);
            *(uint2*)&Xs[r][c4 * 32 + i * 4] = o;
        }
    }
    __syncthreads();   // Xs ready; W(nt0) drained

    bf16x8 aX[4];
#pragma unroll
    for (int k32 = 0; k32 < 4; ++k32)
        aX[k32] = *(const bf16x8*)&Xs[w * 16 + l][k32 * 32 + q * 8];
    __syncthreads();   // all aX reads done: Xs may now be reused as T (z==2)

    int b = m0 >> 10, s0 = m0 & 1023;
    int srow = s0 + w * 16 + l;

    for (int i = 0; i < 8; ++i) {
        int nt = nt0 + i;
        int cur = i & 1;
        if (i) __syncthreads();   // drains W(nt) (covered by prev MFMA phase) + T WAR
        if (i < 7) {
            const short* wsrc = wbase + (nt + 1) * 8192;
#pragma unroll
            for (int k32 = 0; k32 < 4; ++k32)
                dma16(wsrc + k32 * 32, &Ws[cur ^ 1][(w * 4 + k32) * 512]);
        }

        int n0 = nt * 64;
        if (z < 2) {
#pragma unroll
            for (int nb = 0; nb < 4; ++nb) {
                f32x4 c = {0.f, 0.f, 0.f, 0.f};
                const short* wf = &Ws[cur][nb * 2048 + lane * 8];
#pragma unroll
                for (int k32 = 0; k32 < 4; ++k32)
                    c = __builtin_amdgcn_mfma_f32_16x16x32_bf16(*(const bf16x8*)(wf + k32 * 512), aX[k32], c, 0, 0, 0);
                // C^T: lane (l,q) holds n = n0+nb*16+q*4+r, m-row = w*16+l
                const float* bip = &bias[n0 + nb * 16 + q * 4];
                short* dst = (z == 0) ? Qg : Kg;
                int n00 = n0 + nb * 16;
                int hh = n00 >> 7, d0 = (n00 & 127) + q * 4;
                s16x4 ov = { f2bf(c[0] + bip[0]), f2bf(c[1] + bip[1]),
                             f2bf(c[2] + bip[2]), f2bf(c[3] + bip[3]) };
                *(s16x4*)&dst[(((b * 8 + hh) * 1024 + srow) << 7) + d0] = ov;
            }
        } else {
            // V^T: C^T frags -> T[n][m] in LDS, then coalesced row stores
#pragma unroll
            for (int nb = 0; nb < 4; ++nb) {
                f32x4 c = {0.f, 0.f, 0.f, 0.f};
                const short* wf = &Ws[cur][nb * 2048 + lane * 8];
#pragma unroll
                for (int k32 = 0; k32 < 4; ++k32)
                    c = __builtin_amdgcn_mfma_f32_16x16x32_bf16(*(const bf16x8*)(wf + k32 * 512), aX[k32], c, 0, 0, 0);
                const float* bip = &bias[n0 + nb * 16 + q * 4];
#pragma unroll
                for (int r = 0; r < 4; ++r)
                    Tbuf[(nb * 16 + q * 4 + r) * 72 + w * 16 + l] = f2bf(c[r] + bip[r]);
            }
            __syncthreads();   // T ready (also drains W(nt+1) after MFMA cover)
            int nl = t >> 2, mc = t & 3;
            int n = n0 + nl, hh = n >> 7, dd = n & 127;
            uint4 v0 = *(uint4*)&Tbuf[nl * 72 + mc * 16];
            uint4 v1 = *(uint4*)&Tbuf[nl * 72 + mc * 16 + 8];
            uint4* dp = (uint4*)&Vtg[(((b * 8 + hh) * 128 + dd) << 10) + s0 + mc * 16];
            dp[0] = v0; dp[1] = v1;
        }
    }
}

// ----------------------------------------------------------- attention ----
// R10 form (best measured). Flash attention, fixed-max softmax. 128 q-rows/
// block, 4 waves x 32 rows. K dbuf (prefetch kt+1 before QK), V single
// buffer; barrier B sits a full QK/exp phase after DMA issue -> covered
// drains. kf reg-cached per nb, vf (b128, conflict-free) shared across
// strips; P via per-wave LDS; row-sums via MFMA(P, ones).
__global__ __launch_bounds__(256, 2) void attention(
    const short* __restrict__ Qg, const short* __restrict__ Kg,
    const short* __restrict__ Vtg, const int* __restrict__ mask,
    short* __restrict__ AO)
{
    int bh = blockIdx.x & 63;          // q-tiles of one (b,h) share an XCD
    int qt = blockIdx.x >> 6;          // 0..7
    int b = bh >> 3, h = bh & 7;
    int q0 = qt << 7;                  // 128 q-rows per block

    __shared__ __align__(16) short Ks[2][8192];    // blk(nb,k32)=nb*4+k32, +lane*8
    __shared__ __align__(16) short Vs[8192];       // blk(dt,k32)=dt*2+k32, +lane*8
    __shared__ __align__(16) short Ps[4][32][72];  // per-wave P (2 strips)

    int t = threadIdx.x, lane = t & 63, w = t >> 6;
    int l = lane & 15, q = lane >> 4;

    const short* kbase = &Kg[((bh * 1024 + w * 16 + l) << 7) + q * 8];
    const short* vb0 = &Vtg[((bh * 128 + (2 * w) * 16 + l) << 10) + q * 8];
    const short* vb1 = &Vtg[((bh * 128 + (2 * w + 1) * 16 + l) << 10) + q * 8];
    const int* mrow = &mask[b * 1024];

    { // prologue: K(0) -> Ks[0]
        dma16(kbase,      &Ks[0][(w * 4 + 0) * 512]);
        dma16(kbase + 32, &Ks[0][(w * 4 + 1) * 512]);
        dma16(kbase + 64, &Ks[0][(w * 4 + 2) * 512]);
        dma16(kbase + 96, &Ks[0][(w * 4 + 3) * 512]);
    }

    bf16x8 aQ[2][4];
#pragma unroll
    for (int s = 0; s < 2; ++s) {
        const short* qp = &Qg[((bh * 1024 + q0 + w * 32 + s * 16 + l) << 7) + q * 8];
#pragma unroll
        for (int k32 = 0; k32 < 4; ++k32)
            aQ[s][k32] = *(const bf16x8*)(qp + k32 * 32);
    }

    f32x4 O[2][8];
#pragma unroll
    for (int s = 0; s < 2; ++s)
#pragma unroll
        for (int i = 0; i < 8; ++i) O[s][i] = {0.f, 0.f, 0.f, 0.f};
    f32x4 Ls[2] = {{0.f, 0.f, 0.f, 0.f}, {0.f, 0.f, 0.f, 0.f}};

    const short O1 = (short)0x3F80;    // bf16 1.0
    const bf16x8 ONES = {O1, O1, O1, O1, O1, O1, O1, O1};

    const float SL2E = 0.12752298917458827f;  // (1/sqrt(128)) * log2(e)
    const float MAXB = 44.0f;                 // fixed softmax max bound (log2)

    for (int kt = 0; kt < 16; ++kt) {
        int k0 = kt << 6;
        int cur = kt & 1;
        __syncthreads();   // A: prior PV reads of Vs done; K(kt) already drained
        if (kt < 15) {     // prefetch K(kt+1) -> alt buffer
            const short* kp = kbase + (((kt + 1) << 6) << 7);
            dma16(kp,      &Ks[cur ^ 1][(w * 4 + 0) * 512]);
            dma16(kp + 32, &Ks[cur ^ 1][(w * 4 + 1) * 512]);
            dma16(kp + 64, &Ks[cur ^ 1][(w * 4 + 2) * 512]);
            dma16(kp + 96, &Ks[cur ^ 1][(w * 4 + 3) * 512]);
        }
        { // V(kt) -> Vs (drained at barrier B, after the QK/exp phase)
            dma16(vb0 + k0,      &Vs[(4 * w + 0) * 512]);
            dma16(vb0 + k0 + 32, &Vs[(4 * w + 1) * 512]);
            dma16(vb1 + k0,      &Vs[(4 * w + 2) * 512]);
            dma16(vb1 + k0 + 32, &Vs[(4 * w + 3) * 512]);
        }

        int mk[4];
#pragma unroll
        for (int nb = 0; nb < 4; ++nb) mk[nb] = mrow[k0 + nb * 16 + l];
        bool allm = (__ballot(mk[0] && mk[1] && mk[2] && mk[3]) == ~0ull);

        // QK^T + exp2 + P to LDS; kf loaded once per nb, reused for both strips
#pragma unroll
        for (int nb = 0; nb < 4; ++nb) {
            bf16x8 kf[4];
            const short* kfp = &Ks[cur][nb * 2048 + lane * 8];
#pragma unroll
            for (int k32 = 0; k32 < 4; ++k32)
                kf[k32] = *(const bf16x8*)(kfp + k32 * 512);
#pragma unroll
            for (int s = 0; s < 2; ++s) {
                f32x4 c = {0.f, 0.f, 0.f, 0.f};
#pragma unroll
                for (int k32 = 0; k32 < 4; ++k32)
                    c = __builtin_amdgcn_mfma_f32_16x16x32_bf16(aQ[s][k32], kf[k32], c, 0, 0, 0);
#pragma unroll
                for (int r = 0; r < 4; ++r) {
                    float pv = exp2f(fmaf(c[r], SL2E, -MAXB));
                    if (!allm) pv = mk[nb] ? pv : 0.f;
                    Ps[w][s * 16 + q * 4 + r][nb * 16 + l] = f2bf_fast(pv);
                }
            }
        }
        __syncthreads();   // B: drains V(kt) + K(kt+1); covered by QK/exp phase

        bf16x8 aP[2][2];
#pragma unroll
        for (int s = 0; s < 2; ++s) {
            aP[s][0] = *(const bf16x8*)&Ps[w][s * 16 + l][q * 8];
            aP[s][1] = *(const bf16x8*)&Ps[w][s * 16 + l][32 + q * 8];
        }
#pragma unroll
        for (int s = 0; s < 2; ++s) {  // row sums: P @ ones
            Ls[s] = __builtin_amdgcn_mfma_f32_16x16x32_bf16(aP[s][0], ONES, Ls[s], 0, 0, 0);
            Ls[s] = __builtin_amdgcn_mfma_f32_16x16x32_bf16(aP[s][1], ONES, Ls[s], 0, 0, 0);
        }
        // PV: vf loaded once per dt (full-run b128 = conflict-free)
#pragma unroll
        for (int dt = 0; dt < 8; ++dt) {
            bf16x8 vf0 = *(const bf16x8*)&Vs[(dt * 2 + 0) * 512 + lane * 8];
            bf16x8 vf1 = *(const bf16x8*)&Vs[(dt * 2 + 1) * 512 + lane * 8];
#pragma unroll
            for (int s = 0; s < 2; ++s) {
                f32x4 c = O[s][dt];
                c = __builtin_amdgcn_mfma_f32_16x16x32_bf16(aP[s][0], vf0, c, 0, 0, 0);
                c = __builtin_amdgcn_mfma_f32_16x16x32_bf16(aP[s][1], vf1, c, 0, 0, 0);
                O[s][dt] = c;
            }
        }
    }

#pragma unroll
    for (int s = 0; s < 2; ++s) {
        float rl[4];
#pragma unroll
        for (int r = 0; r < 4; ++r) rl[r] = 1.0f / Ls[s][r];
#pragma unroll
        for (int dt = 0; dt < 8; ++dt) {
            int col = h * 128 + dt * 16 + l;
#pragma unroll
            for (int r = 0; r < 4; ++r) {
                int srow = q0 + w * 32 + s * 16 + q * 4 + r;
                AO[((b * 1024 + srow) << 10) + col] = f2bf(O[s][dt][r] * rl[r]);
            }
        }
    }
}

// ------------------------------------------------------------ out proj ----
// C^T orientation (A=WoT-frag, B=AO-frag) -> float4 stores. 16-row m-tiles,
// grid 512. Double-buffered As (VGPR-parked) + Bs (DMA): 1 barrier/kc.
__global__ __launch_bounds__(256) void out_proj(
    const short* __restrict__ AO, const short* __restrict__ WoT,
    const float* __restrict__ bo, float* __restrict__ out)
{
    __shared__ __align__(16) short As[2][16][72];
    __shared__ __align__(16) short Bs[2][8192];   // blk(nb,k32)=nb*2+k32, nb 0..7

    int t = threadIdx.x, lane = t & 63, w = t >> 6;
    int l = lane & 15, q = lane >> 4;
    int m0 = blockIdx.x * 16;

    int ar = t >> 3, ac8 = t & 7;
    {
        if (t < 128)
            *(uint4*)&As[0][ar][ac8 * 8] = *(const uint4*)&AO[((m0 + ar) << 10) + ac8 * 8];
#pragma unroll
        for (int j = 0; j < 4; ++j) {
            int nb = 2 * w + (j >> 1), k32 = j & 1;
            dma16(&WoT[(nb * 16 + l) * 1024 + k32 * 32 + q * 8], &Bs[0][(nb * 2 + k32) * 512]);
        }
    }

    f32x4 acc[2];
    acc[0] = {0.f, 0.f, 0.f, 0.f};
    acc[1] = {0.f, 0.f, 0.f, 0.f};

    for (int kc = 0; kc < 16; ++kc) {
        __syncthreads();
        int cur = kc & 1;
        uint4 anext;
        if (kc < 15) {
            int k1 = (kc + 1) * 64;
            if (t < 128)
                anext = *(const uint4*)&AO[((m0 + ar) << 10) + k1 + ac8 * 8];
#pragma unroll
            for (int j = 0; j < 4; ++j) {
                int nb = 2 * w + (j >> 1), k32 = j & 1;
                dma16(&WoT[(nb * 16 + l) * 1024 + k1 + k32 * 32 + q * 8],
                      &Bs[cur ^ 1][(nb * 2 + k32) * 512]);
            }
        }

        bf16x8 aA0 = *(const bf16x8*)&As[cur][l][q * 8];
        bf16x8 aA1 = *(const bf16x8*)&As[cur][l][32 + q * 8];
#pragma unroll
        for (int nb = 0; nb < 2; ++nb) {
            int nbg = 2 * w + nb;
            f32x4 c = acc[nb];
            c = __builtin_amdgcn_mfma_f32_16x16x32_bf16(*(const bf16x8*)&Bs[cur][(nbg * 2 + 0) * 512 + lane * 8], aA0, c, 0, 0, 0);
            c = __builtin_amdgcn_mfma_f32_16x16x32_bf16(*(const bf16x8*)&Bs[cur][(nbg * 2 + 1) * 512 + lane * 8], aA1, c, 0, 0, 0);
            acc[nb] = c;
        }

        if (kc < 15 && t < 128)
            *(uint4*)&As[cur ^ 1][ar][ac8 * 8] = anext;
    }

    // C^T: lane (l,q) holds out[n=(2w+nb)*16+q*4+r][m=m0+l] -> float4 stores
#pragma unroll
    for (int nb = 0; nb < 2; ++nb) {
        int n0 = (2 * w + nb) * 16 + q * 4;
        const float* bop = &bo[n0];
        float4 ov = { acc[nb][0] + bop[0], acc[nb][1] + bop[1],
                      acc[nb][2] + bop[2], acc[nb][3] + bop[3] };
        *(float4*)&out[((m0 + l) << 7) + n0] = ov;
    }
}

// -------------------------------------------------------------- launch ----
extern "C" void kernel_launch(void* const* d_in, const int* in_sizes, int n_in,
                              void* d_out, int out_size, void* d_ws, size_t ws_size,
                              hipStream_t stream)
{
    const size_t NEED = (size_t)65 * 1024 * 1024;
    if (ws_size < NEED) {
        hipLaunchKernelGGL(fill_sentinel, dim3((out_size + 255) / 256), dim3(256), 0, stream,
                           (float*)d_out, out_size);
        return;
    }

    const float* query = (const float*)d_in[0];
    const float* key_  = (const float*)d_in[1];
    const float* value = (const float*)d_in[2];
    const float* pos   = (const float*)d_in[3];
    const int*   mask  = (const int*)d_in[4];
    const float* Wq = (const float*)d_in[5];
    const float* bq = (const float*)d_in[6];
    const float* Wk = (const float*)d_in[7];
    const float* bk = (const float*)d_in[8];
    const float* Wv = (const float*)d_in[9];
    const float* bv = (const float*)d_in[10];
    const float* Wo = (const float*)d_in[11];
    const float* bo = (const float*)d_in[12];

    char* ws = (char*)d_ws;
    short* Qg  = (short*)(ws);
    short* Kg  = (short*)(ws + (size_t)16 * 1024 * 1024);
    short* Vtg = (short*)(ws + (size_t)32 * 1024 * 1024);
    short* AO  = (short*)(ws + (size_t)48 * 1024 * 1024);
    short* WTq = (short*)(ws + (size_t)64 * 1024 * 1024);
    short* WTk = WTq + 131072;
    short* WTv = WTk + 131072;
    short* WoT = WTv + 131072;

    hipLaunchKernelGGL(transpose_w, dim3(32, 4), dim3(256), 0, stream,
                       Wq, Wk, Wv, Wo, WTq, WTk, WTv, WoT);
    hipLaunchKernelGGL(qkv_proj, dim3(256, 3), dim3(256), 0, stream,
                       query, key_, value, pos, WTq, WTk, WTv, bq, bk, bv, Qg, Kg, Vtg);
    hipLaunchKernelGGL(attention, dim3(512), dim3(256), 0, stream,
                       Qg, Kg, Vtg, mask, AO);
    hipLaunchKernelGGL(out_proj, dim3(512), dim3(256), 0, stream,
                       AO, WoT, bo, (float*)d_out);
}